// Round 2
// baseline (3149.876 us; speedup 1.0000x reference)
//
#include <hip/hip_runtime.h>

#define B_DIM 16
#define S_DIM 4096
#define N_DIM 256
#define EPS 1e-5f

// ---------------------------------------------------------------------------
// Tiled f32 GEMM: Y[M,256] = X[M,256] @ W[256,256]^T + bias   (unchanged)
// ---------------------------------------------------------------------------
__global__ __launch_bounds__(256)
void gemm_xwT_bias(const float* __restrict__ X,
                   const float* __restrict__ W,
                   const float* __restrict__ bias,
                   float* __restrict__ Y,
                   int M)
{
    __shared__ float Xs[16][68];
    __shared__ float Ws[16][68];

    const int tid = threadIdx.x;
    const int m0 = blockIdx.x * 64;
    const int n0 = blockIdx.y * 64;
    const int tx = tid & 15;
    const int ty = tid >> 4;

    float acc[4][4] = {};

    for (int k0 = 0; k0 < 256; k0 += 16) {
        {
            const int r  = tid >> 2;
            const int kk = (tid & 3) * 4;
            float4 v = *(const float4*)(X + (size_t)(m0 + r) * 256 + k0 + kk);
            Xs[kk + 0][r] = v.x; Xs[kk + 1][r] = v.y;
            Xs[kk + 2][r] = v.z; Xs[kk + 3][r] = v.w;
            float4 w = *(const float4*)(W + (size_t)(n0 + r) * 256 + k0 + kk);
            Ws[kk + 0][r] = w.x; Ws[kk + 1][r] = w.y;
            Ws[kk + 2][r] = w.z; Ws[kk + 3][r] = w.w;
        }
        __syncthreads();

        #pragma unroll
        for (int k = 0; k < 16; ++k) {
            float4 xv = *(const float4*)&Xs[k][ty * 4];
            float4 wv = *(const float4*)&Ws[k][tx * 4];
            float xa[4] = {xv.x, xv.y, xv.z, xv.w};
            float wa[4] = {wv.x, wv.y, wv.z, wv.w};
            #pragma unroll
            for (int i = 0; i < 4; ++i)
                #pragma unroll
                for (int j = 0; j < 4; ++j)
                    acc[i][j] += xa[i] * wa[j];
        }
        __syncthreads();
    }

    const int nbase = n0 + tx * 4;
    float4 bv = *(const float4*)(bias + nbase);
    #pragma unroll
    for (int i = 0; i < 4; ++i) {
        const int m = m0 + ty * 4 + i;
        float4 o;
        o.x = acc[i][0] + bv.x;
        o.y = acc[i][1] + bv.y;
        o.z = acc[i][2] + bv.z;
        o.w = acc[i][3] + bv.w;
        *(float4*)(Y + (size_t)m * 256 + nbase) = o;
    }
}

// ---------------------------------------------------------------------------
// DPP helpers: canonical wave64 sum (valid in lane 63), VALU pipe only.
// ---------------------------------------------------------------------------
template<int CTRL>
__device__ __forceinline__ float dpp_term(float x) {
    return __int_as_float(
        __builtin_amdgcn_update_dpp(0, __float_as_int(x), CTRL, 0xF, 0xF, true));
}

__device__ __forceinline__ float wave_sum_l63(float v) {
    v += dpp_term<0x111>(v);   // row_shr:1
    v += dpp_term<0x112>(v);   // row_shr:2
    v += dpp_term<0x114>(v);   // row_shr:4
    v += dpp_term<0x118>(v);   // row_shr:8
    v += dpp_term<0x142>(v);   // row_bcast:15
    v += dpp_term<0x143>(v);   // row_bcast:31
    return v;
}

__device__ __forceinline__ float readlane63(float x) {
    return __int_as_float(__builtin_amdgcn_readlane(__float_as_int(x), 63));
}

// ---------------------------------------------------------------------------
// Sequential scan, v4: one workgroup (512 threads, 8 waves) per batch.
//
// Decomposition: wave w owns K-slice [32w, 32w+32); lane l owns output rows
// 4l..4l+3. After the partial reduce, the FULL 256-float v vector lives in
// wave 0 (4 consecutive outputs per lane):
//   - LN stats are a single-wave DPP reduce + readlane  -> no cross-wave
//     s_red LDS round trip, no third barrier.
//   - 2 barriers/step instead of 3.
// Barriers are raw s_barrier with producer-side lgkmcnt(0) only (m201
// pattern): NO vmcnt drain in the loop, so the Bu prefetch (2 steps ahead)
// and the global state stores float across barriers instead of being
// force-drained 3x/step by __syncthreads.
//
// Per-thread A fragment: rows {4l..4l+3} x cols [32w,32w+32) = 128 floats in
// 32 float4 VGPRs (~200 VGPR total, fits the 256 cap at 2 waves/SIMD).
// All LDS traffic is b128 and conflict-free:
//   partial write: wave-contiguous 1024 B; partial read: 8x contiguous 1024 B;
//   state read: pure same-address broadcast per wave.
// ---------------------------------------------------------------------------
__global__ __launch_bounds__(512, 2)
void scan_kernel(const float* __restrict__ A,     // [256,256]
                 const float* __restrict__ Bu,    // [16,4096,256]
                 const float* __restrict__ ln_g,
                 const float* __restrict__ ln_b,
                 float* __restrict__ states)      // [16,4096,256]
{
    const int b = blockIdx.x;
    const int t = threadIdx.x;
    const int w = t >> 6;        // wave 0..7  -> K-slice [32w, 32w+32)
    const int l = t & 63;        // lane       -> output rows 4l..4l+3

    __shared__ float s_state[256];
    __shared__ float s_partial[8][256];   // [wave][output]

    // --- A fragment -> 128 VGPRs: A[4l+j][32w + 4c + i]
    float4 a4[4][8];
    #pragma unroll
    for (int j = 0; j < 4; ++j) {
        const float* arow = A + (size_t)(4 * l + j) * 256 + 32 * w;
        #pragma unroll
        for (int c = 0; c < 8; ++c)
            a4[j][c] = ((const float4*)arow)[c];
    }

    const bool red = (w == 0);

    const float* bu_base  = Bu + (size_t)b * S_DIM * N_DIM;
    float*       out_base = states + (size_t)b * S_DIM * N_DIM;

    float4 g4  = make_float4(0.f, 0.f, 0.f, 0.f);
    float4 be4 = g4;
    float4 bu0 = g4, bu1 = g4;
    if (red) {
        g4  = ((const float4*)ln_g)[l];
        be4 = ((const float4*)ln_b)[l];
        bu0 = ((const float4*)bu_base)[l];
        bu1 = ((const float4*)(bu_base + N_DIM))[l];
        ((float4*)s_state)[l] = make_float4(0.f, 0.f, 0.f, 0.f);
    }
    __syncthreads();   // prologue only

    for (int step = 0; step < S_DIM; ++step) {
        // Prefetch Bu for step+2: issued here, used two iterations later.
        // No barrier in this loop drains vmcnt, so latency is truly hidden.
        float4 bu2 = make_float4(0.f, 0.f, 0.f, 0.f);
        if (red && (step + 2 < S_DIM))
            bu2 = ((const float4*)(bu_base + (size_t)(step + 2) * N_DIM))[l];

        // --- ph1: partial matvec over this wave's 32-col K-slice ---
        const float4* sp = (const float4*)(s_state + 32 * w);  // broadcast reads
        float accA[4] = {0.f, 0.f, 0.f, 0.f};
        float accB[4] = {0.f, 0.f, 0.f, 0.f};   // 2 chains/row: halve dep depth
        #pragma unroll
        for (int c = 0; c < 8; ++c) {
            const float4 sc = sp[c];
            #pragma unroll
            for (int j = 0; j < 4; ++j) {
                const float4 a = a4[j][c];
                if (c & 1) {
                    accB[j] = fmaf(a.x, sc.x, accB[j]);
                    accB[j] = fmaf(a.y, sc.y, accB[j]);
                    accB[j] = fmaf(a.z, sc.z, accB[j]);
                    accB[j] = fmaf(a.w, sc.w, accB[j]);
                } else {
                    accA[j] = fmaf(a.x, sc.x, accA[j]);
                    accA[j] = fmaf(a.y, sc.y, accA[j]);
                    accA[j] = fmaf(a.z, sc.z, accA[j]);
                    accA[j] = fmaf(a.w, sc.w, accA[j]);
                }
            }
        }
        float4 pr;
        pr.x = accA[0] + accB[0];
        pr.y = accA[1] + accB[1];
        pr.z = accA[2] + accB[2];
        pr.w = accA[3] + accB[3];
        *(float4*)&s_partial[w][4 * l] = pr;

        asm volatile("s_waitcnt lgkmcnt(0)" ::: "memory");  // partial write landed
        __builtin_amdgcn_s_barrier();

        // --- ph2: wave 0 only — reduce K-partials, LN, write state ---
        if (red) {
            const float* prow = &s_partial[0][4 * l];
            const float4 q0 = *(const float4*)(prow + 0 * 256);
            const float4 q1 = *(const float4*)(prow + 1 * 256);
            const float4 q2 = *(const float4*)(prow + 2 * 256);
            const float4 q3 = *(const float4*)(prow + 3 * 256);
            const float4 q4 = *(const float4*)(prow + 4 * 256);
            const float4 q5 = *(const float4*)(prow + 5 * 256);
            const float4 q6 = *(const float4*)(prow + 6 * 256);
            const float4 q7 = *(const float4*)(prow + 7 * 256);

            float4 v;
            v.x = ((q0.x + q1.x) + (q2.x + q3.x)) + ((q4.x + q5.x) + (q6.x + q7.x)) + bu0.x;
            v.y = ((q0.y + q1.y) + (q2.y + q3.y)) + ((q4.y + q5.y) + (q6.y + q7.y)) + bu0.y;
            v.z = ((q0.z + q1.z) + (q2.z + q3.z)) + ((q4.z + q5.z) + (q6.z + q7.z)) + bu0.z;
            v.w = ((q0.w + q1.w) + (q2.w + q3.w)) + ((q4.w + q5.w) + (q6.w + q7.w)) + bu0.w;

            const float sv = (v.x + v.y) + (v.z + v.w);
            const float sq = fmaf(v.x, v.x, fmaf(v.y, v.y, fmaf(v.z, v.z, v.w * v.w)));

            const float tot  = readlane63(wave_sum_l63(sv));
            const float tot2 = readlane63(wave_sum_l63(sq));

            const float mu  = tot * (1.0f / 256.0f);
            const float var = tot2 * (1.0f / 256.0f) - mu * mu;
            const float inv = rsqrtf(var + EPS);

            float4 y;
            y.x = fmaxf((v.x - mu) * inv * g4.x + be4.x, 0.0f);
            y.y = fmaxf((v.y - mu) * inv * g4.y + be4.y, 0.0f);
            y.z = fmaxf((v.z - mu) * inv * g4.z + be4.z, 0.0f);
            y.w = fmaxf((v.w - mu) * inv * g4.w + be4.w, 0.0f);

            ((float4*)s_state)[l] = y;
            *(float4*)(out_base + (size_t)step * N_DIM + 4 * l) = y;  // fire & forget

            bu0 = bu1;
            bu1 = bu2;
        }

        asm volatile("s_waitcnt lgkmcnt(0)" ::: "memory");  // state write landed
        __builtin_amdgcn_s_barrier();
    }
}

// ---------------------------------------------------------------------------
extern "C" void kernel_launch(void* const* d_in, const int* in_sizes, int n_in,
                              void* d_out, int out_size, void* d_ws, size_t ws_size,
                              hipStream_t stream)
{
    const float* u    = (const float*)d_in[0];
    const float* A    = (const float*)d_in[1];
    const float* B_w  = (const float*)d_in[2];
    const float* B_b  = (const float*)d_in[3];
    const float* ln_g = (const float*)d_in[4];
    const float* ln_b = (const float*)d_in[5];
    const float* C_w  = (const float*)d_in[6];
    const float* C_b  = (const float*)d_in[7];

    float* states  = (float*)d_out;
    float* outputs = (float*)d_out + (size_t)B_DIM * S_DIM * N_DIM;

    // Stage Bu in the outputs region (dead until kernel 3 overwrites it).
    float* Bu = outputs;

    const int M = B_DIM * S_DIM;   // 65536

    // 1) Bu = u @ B_w^T + B_b
    {
        dim3 grid(M / 64, N_DIM / 64);
        hipLaunchKernelGGL(gemm_xwT_bias, grid, dim3(256), 0, stream,
                           u, B_w, B_b, Bu, M);
    }

    // 2) sequential scan -> states
    {
        hipLaunchKernelGGL(scan_kernel, dim3(B_DIM), dim3(512), 0, stream,
                           A, Bu, ln_g, ln_b, states);
    }

    // 3) outputs = states @ C_w^T + C_b
    {
        dim3 grid(M / 64, N_DIM / 64);
        hipLaunchKernelGGL(gemm_xwT_bias, grid, dim3(256), 0, stream,
                           states, C_w, C_b, outputs, M);
    }
}

// Round 7
// 3141.536 us; speedup vs baseline: 1.0027x; 1.0027x over previous
//
#include <hip/hip_runtime.h>

#define B_DIM 16
#define S_DIM 4096
#define N_DIM 256
#define EPS 1e-5f

// ---------------------------------------------------------------------------
// Tiled f32 GEMM: Y[M,256] = X[M,256] @ W[256,256]^T + bias   (unchanged)
// ---------------------------------------------------------------------------
__global__ __launch_bounds__(256)
void gemm_xwT_bias(const float* __restrict__ X,
                   const float* __restrict__ W,
                   const float* __restrict__ bias,
                   float* __restrict__ Y,
                   int M)
{
    __shared__ float Xs[16][68];
    __shared__ float Ws[16][68];

    const int tid = threadIdx.x;
    const int m0 = blockIdx.x * 64;
    const int n0 = blockIdx.y * 64;
    const int tx = tid & 15;
    const int ty = tid >> 4;

    float acc[4][4] = {};

    for (int k0 = 0; k0 < 256; k0 += 16) {
        {
            const int r  = tid >> 2;
            const int kk = (tid & 3) * 4;
            float4 v = *(const float4*)(X + (size_t)(m0 + r) * 256 + k0 + kk);
            Xs[kk + 0][r] = v.x; Xs[kk + 1][r] = v.y;
            Xs[kk + 2][r] = v.z; Xs[kk + 3][r] = v.w;
            float4 w = *(const float4*)(W + (size_t)(n0 + r) * 256 + k0 + kk);
            Ws[kk + 0][r] = w.x; Ws[kk + 1][r] = w.y;
            Ws[kk + 2][r] = w.z; Ws[kk + 3][r] = w.w;
        }
        __syncthreads();

        #pragma unroll
        for (int k = 0; k < 16; ++k) {
            float4 xv = *(const float4*)&Xs[k][ty * 4];
            float4 wv = *(const float4*)&Ws[k][tx * 4];
            float xa[4] = {xv.x, xv.y, xv.z, xv.w};
            float wa[4] = {wv.x, wv.y, wv.z, wv.w};
            #pragma unroll
            for (int i = 0; i < 4; ++i)
                #pragma unroll
                for (int j = 0; j < 4; ++j)
                    acc[i][j] += xa[i] * wa[j];
        }
        __syncthreads();
    }

    const int nbase = n0 + tx * 4;
    float4 bv = *(const float4*)(bias + nbase);
    #pragma unroll
    for (int i = 0; i < 4; ++i) {
        const int m = m0 + ty * 4 + i;
        float4 o;
        o.x = acc[i][0] + bv.x;
        o.y = acc[i][1] + bv.y;
        o.z = acc[i][2] + bv.z;
        o.w = acc[i][3] + bv.w;
        *(float4*)(Y + (size_t)m * 256 + nbase) = o;
    }
}

// ---------------------------------------------------------------------------
// DPP helpers: canonical wave64 sum (valid in lane 63), VALU pipe only.
// ---------------------------------------------------------------------------
template<int CTRL>
__device__ __forceinline__ float dpp_term(float x) {
    return __int_as_float(
        __builtin_amdgcn_update_dpp(0, __float_as_int(x), CTRL, 0xF, 0xF, true));
}

__device__ __forceinline__ float wave_sum_l63(float v) {
    v += dpp_term<0x111>(v);   // row_shr:1
    v += dpp_term<0x112>(v);   // row_shr:2
    v += dpp_term<0x114>(v);   // row_shr:4
    v += dpp_term<0x118>(v);   // row_shr:8
    v += dpp_term<0x142>(v);   // row_bcast:15
    v += dpp_term<0x143>(v);   // row_bcast:31
    return v;
}

__device__ __forceinline__ float readlane63(float x) {
    return __int_as_float(__builtin_amdgcn_readlane(__float_as_int(x), 63));
}

// ---------------------------------------------------------------------------
// Sequential scan, v5 = v4 + A-fragment register pinning.
//
// v4 measurement (R2): VGPR_Count=96 — the 128-float A fragment was NOT
// register-resident; the compiler rematerialized A inside the step loop
// (L2-hot, so invisible in FETCH_SIZE, but ~600 cy/step on the serial
// chain: extra issue slots + L2 latency/BW). Fix: empty asm volatile
// "+v" pins after the prologue loads — the asm can't be rematerialized
// or sunk, so the values must stay live in VGPRs (~200 total < 256 cap
// at 2 waves/SIMD).
//
// Decomposition (unchanged from v4): wave w owns K-slice [32w, 32w+32);
// lane l owns output rows 4l..4l+3. Full v vector lands in wave 0 ->
// single-wave DPP LN stats, 2 raw s_barriers/step, no vmcnt drain in
// the loop (Bu prefetch + state stores float across barriers).
// ---------------------------------------------------------------------------
__global__ __launch_bounds__(512, 2)
void scan_kernel(const float* __restrict__ A,     // [256,256]
                 const float* __restrict__ Bu,    // [16,4096,256]
                 const float* __restrict__ ln_g,
                 const float* __restrict__ ln_b,
                 float* __restrict__ states)      // [16,4096,256]
{
    const int b = blockIdx.x;
    const int t = threadIdx.x;
    const int w = t >> 6;        // wave 0..7  -> K-slice [32w, 32w+32)
    const int l = t & 63;        // lane       -> output rows 4l..4l+3

    __shared__ float s_state[256];
    __shared__ float s_partial[8][256];   // [wave][output]

    // --- A fragment -> 128 VGPRs: A[4l+j][32w + 4c + i]
    float4 a4[4][8];
    #pragma unroll
    for (int j = 0; j < 4; ++j) {
        const float* arow = A + (size_t)(4 * l + j) * 256 + 32 * w;
        #pragma unroll
        for (int c = 0; c < 8; ++c)
            a4[j][c] = ((const float4*)arow)[c];
    }
    // Pin every component into a VGPR: the asm is opaque, cannot be
    // rematerialized, and cannot be sunk into the loop -> the compiler
    // must keep the fragment register-resident instead of re-loading A
    // from memory every step (the v4 96-VGPR failure mode).
    #pragma unroll
    for (int j = 0; j < 4; ++j)
        #pragma unroll
        for (int c = 0; c < 8; ++c)
            asm volatile("" : "+v"(a4[j][c].x), "+v"(a4[j][c].y),
                              "+v"(a4[j][c].z), "+v"(a4[j][c].w));

    const bool red = (w == 0);

    const float* bu_base  = Bu + (size_t)b * S_DIM * N_DIM;
    float*       out_base = states + (size_t)b * S_DIM * N_DIM;

    float4 g4  = make_float4(0.f, 0.f, 0.f, 0.f);
    float4 be4 = g4;
    float4 bu0 = g4, bu1 = g4;
    if (red) {
        g4  = ((const float4*)ln_g)[l];
        be4 = ((const float4*)ln_b)[l];
        bu0 = ((const float4*)bu_base)[l];
        bu1 = ((const float4*)(bu_base + N_DIM))[l];
        ((float4*)s_state)[l] = make_float4(0.f, 0.f, 0.f, 0.f);
    }
    __syncthreads();   // prologue only

    for (int step = 0; step < S_DIM; ++step) {
        // Prefetch Bu for step+2: issued here, used two iterations later.
        // No barrier in this loop drains vmcnt, so latency is truly hidden.
        float4 bu2 = make_float4(0.f, 0.f, 0.f, 0.f);
        if (red && (step + 2 < S_DIM))
            bu2 = ((const float4*)(bu_base + (size_t)(step + 2) * N_DIM))[l];

        // --- ph1: partial matvec over this wave's 32-col K-slice ---
        const float4* sp = (const float4*)(s_state + 32 * w);  // broadcast reads
        float accA[4] = {0.f, 0.f, 0.f, 0.f};
        float accB[4] = {0.f, 0.f, 0.f, 0.f};   // 2 chains/row: halve dep depth
        #pragma unroll
        for (int c = 0; c < 8; ++c) {
            const float4 sc = sp[c];
            #pragma unroll
            for (int j = 0; j < 4; ++j) {
                const float4 a = a4[j][c];
                if (c & 1) {
                    accB[j] = fmaf(a.x, sc.x, accB[j]);
                    accB[j] = fmaf(a.y, sc.y, accB[j]);
                    accB[j] = fmaf(a.z, sc.z, accB[j]);
                    accB[j] = fmaf(a.w, sc.w, accB[j]);
                } else {
                    accA[j] = fmaf(a.x, sc.x, accA[j]);
                    accA[j] = fmaf(a.y, sc.y, accA[j]);
                    accA[j] = fmaf(a.z, sc.z, accA[j]);
                    accA[j] = fmaf(a.w, sc.w, accA[j]);
                }
            }
        }
        float4 pr;
        pr.x = accA[0] + accB[0];
        pr.y = accA[1] + accB[1];
        pr.z = accA[2] + accB[2];
        pr.w = accA[3] + accB[3];
        *(float4*)&s_partial[w][4 * l] = pr;

        asm volatile("s_waitcnt lgkmcnt(0)" ::: "memory");  // partial write landed
        __builtin_amdgcn_s_barrier();

        // --- ph2: wave 0 only — reduce K-partials, LN, write state ---
        if (red) {
            const float* prow = &s_partial[0][4 * l];
            const float4 q0 = *(const float4*)(prow + 0 * 256);
            const float4 q1 = *(const float4*)(prow + 1 * 256);
            const float4 q2 = *(const float4*)(prow + 2 * 256);
            const float4 q3 = *(const float4*)(prow + 3 * 256);
            const float4 q4 = *(const float4*)(prow + 4 * 256);
            const float4 q5 = *(const float4*)(prow + 5 * 256);
            const float4 q6 = *(const float4*)(prow + 6 * 256);
            const float4 q7 = *(const float4*)(prow + 7 * 256);

            float4 v;
            v.x = ((q0.x + q1.x) + (q2.x + q3.x)) + ((q4.x + q5.x) + (q6.x + q7.x)) + bu0.x;
            v.y = ((q0.y + q1.y) + (q2.y + q3.y)) + ((q4.y + q5.y) + (q6.y + q7.y)) + bu0.y;
            v.z = ((q0.z + q1.z) + (q2.z + q3.z)) + ((q4.z + q5.z) + (q6.z + q7.z)) + bu0.z;
            v.w = ((q0.w + q1.w) + (q2.w + q3.w)) + ((q4.w + q5.w) + (q6.w + q7.w)) + bu0.w;

            const float sv = (v.x + v.y) + (v.z + v.w);
            const float sq = fmaf(v.x, v.x, fmaf(v.y, v.y, fmaf(v.z, v.z, v.w * v.w)));

            const float tot  = readlane63(wave_sum_l63(sv));
            const float tot2 = readlane63(wave_sum_l63(sq));

            const float mu  = tot * (1.0f / 256.0f);
            const float var = tot2 * (1.0f / 256.0f) - mu * mu;
            const float inv = rsqrtf(var + EPS);

            float4 y;
            y.x = fmaxf((v.x - mu) * inv * g4.x + be4.x, 0.0f);
            y.y = fmaxf((v.y - mu) * inv * g4.y + be4.y, 0.0f);
            y.z = fmaxf((v.z - mu) * inv * g4.z + be4.z, 0.0f);
            y.w = fmaxf((v.w - mu) * inv * g4.w + be4.w, 0.0f);

            ((float4*)s_state)[l] = y;
            *(float4*)(out_base + (size_t)step * N_DIM + 4 * l) = y;  // fire & forget

            bu0 = bu1;
            bu1 = bu2;
        }

        asm volatile("s_waitcnt lgkmcnt(0)" ::: "memory");  // state write landed
        __builtin_amdgcn_s_barrier();
    }
}

// ---------------------------------------------------------------------------
extern "C" void kernel_launch(void* const* d_in, const int* in_sizes, int n_in,
                              void* d_out, int out_size, void* d_ws, size_t ws_size,
                              hipStream_t stream)
{
    const float* u    = (const float*)d_in[0];
    const float* A    = (const float*)d_in[1];
    const float* B_w  = (const float*)d_in[2];
    const float* B_b  = (const float*)d_in[3];
    const float* ln_g = (const float*)d_in[4];
    const float* ln_b = (const float*)d_in[5];
    const float* C_w  = (const float*)d_in[6];
    const float* C_b  = (const float*)d_in[7];

    float* states  = (float*)d_out;
    float* outputs = (float*)d_out + (size_t)B_DIM * S_DIM * N_DIM;

    // Stage Bu in the outputs region (dead until kernel 3 overwrites it).
    float* Bu = outputs;

    const int M = B_DIM * S_DIM;   // 65536

    // 1) Bu = u @ B_w^T + B_b
    {
        dim3 grid(M / 64, N_DIM / 64);
        hipLaunchKernelGGL(gemm_xwT_bias, grid, dim3(256), 0, stream,
                           u, B_w, B_b, Bu, M);
    }

    // 2) sequential scan -> states
    {
        hipLaunchKernelGGL(scan_kernel, dim3(B_DIM), dim3(512), 0, stream,
                           A, Bu, ln_g, ln_b, states);
    }

    // 3) outputs = states @ C_w^T + C_b
    {
        dim3 grid(M / 64, N_DIM / 64);
        hipLaunchKernelGGL(gemm_xwT_bias, grid, dim3(256), 0, stream,
                           states, C_w, C_b, outputs, M);
    }
}